// Round 2
// baseline (224.113 us; speedup 1.0000x reference)
//
#include <hip/hip_runtime.h>
#include <hip/hip_bf16.h>

#define BB 64
#define SS 2048
#define DD 512
#define MTOT (BB * SS)          // 131072 rows

typedef __attribute__((ext_vector_type(8))) short short8;            // 8 bf16
typedef __attribute__((ext_vector_type(8))) unsigned short ushort8;
typedef __attribute__((ext_vector_type(4))) float f32x4;

__device__ __forceinline__ unsigned short f2bf(float f){
  union { float f; unsigned int u; } a; a.f = f;
  unsigned int r = a.u + 0x7fffu + ((a.u >> 16) & 1u);  // RNE
  return (unsigned short)(r >> 16);
}

__device__ __forceinline__ ushort8 pack8(float4 a, float4 b){
  ushort8 u;
  u[0]=f2bf(a.x); u[1]=f2bf(a.y); u[2]=f2bf(a.z); u[3]=f2bf(a.w);
  u[4]=f2bf(b.x); u[5]=f2bf(b.y); u[6]=f2bf(b.z); u[7]=f2bf(b.w);
  return u;
}

// ---- kernel 1: W1 fp32 -> bf16 ([e][d], K-contiguous) ----
__global__ void cvt_w1_kernel(const float* __restrict__ W1, unsigned short* __restrict__ W1b){
  int i = blockIdx.x * blockDim.x + threadIdx.x;   // 65536 threads
  #pragma unroll
  for (int j = 0; j < 4; ++j){
    int idx = i + j * 65536;
    W1b[idx] = f2bf(W1[idx]);
  }
}

// ---- kernel 2: partial scores over one 256-wide e-chunk ----
// Block: 256 thr (4 waves). BM=64 rows, BE=256 e (wave wv owns 64 e).
// Per-wave tile 64x64 -> acc[4][4] f32x4 = 64 regs. K in 4 phases of 128,
// double-buffered swizzled LDS, reg-staged issue-early/write-late,
// B ping-pong prefetch, setprio around MFMA clusters.
__launch_bounds__(256, 3)
__global__ void scores_kernel(const float* __restrict__ x,
                              const unsigned short* __restrict__ W1b,
                              const float* __restrict__ b1,
                              const float* __restrict__ w2,
                              float* __restrict__ scorep){
  __shared__ __align__(16) unsigned short xs[2][64 * 128];   // 2 x 16KB

  const int t    = threadIdx.x;
  const int lane = t & 63;
  const int wv   = t >> 6;                 // 0..3 -> e sub-range
  const int bid  = blockIdx.x;
  const int ec   = bid & 1;                // e-chunk 0/1
  const int m0   = (bid >> 1) * 64;

  f32x4 acc[4][4];
  #pragma unroll
  for (int mt = 0; mt < 4; ++mt)
    #pragma unroll
    for (int et = 0; et < 4; ++et)
      acc[mt][et] = (f32x4){0.f, 0.f, 0.f, 0.f};

  // staging map: row = i*16 + (t>>4), k-chunk = t&15 (8 floats)
  const int srow = t >> 4;                 // 0..15
  const int scc  = t & 15;
  const int swz  = (srow & 7) << 4;        // row&7 const across i (i*16 % 8 == 0)

  const int arow = lane & 15;              // frag row/col within 16
  const int kgrp = lane >> 4;              // 0..3 -> k sub-offset *8
  const int ebase = ec * 256 + wv * 64;    // this wave's e origin

  // prologue: stage phase 0
  #pragma unroll
  for (int i = 0; i < 4; ++i){
    int row = i * 16 + srow;
    const float* src = x + (size_t)(m0 + row) * DD + scc * 8;
    float4 f0 = *(const float4*)src;
    float4 f1 = *(const float4*)(src + 4);
    *(ushort8*)((char*)&xs[0][0] + row * 256 + ((scc << 4) ^ swz)) = pack8(f0, f1);
  }
  // B ping-pong: preload ks=0
  short8 bb[2][4];
  #pragma unroll
  for (int et = 0; et < 4; ++et)
    bb[0][et] = *(const short8*)(W1b + (size_t)(ebase + et * 16 + arow) * DD + kgrp * 8);
  __syncthreads();

  #pragma unroll
  for (int p = 0; p < 4; ++p){
    // issue next-phase x loads early (complete under this phase's MFMA)
    float4 nf[8];
    if (p < 3){
      #pragma unroll
      for (int i = 0; i < 4; ++i){
        int row = i * 16 + srow;
        const float* src = x + (size_t)(m0 + row) * DD + (p + 1) * 128 + scc * 8;
        nf[2*i]   = *(const float4*)src;
        nf[2*i+1] = *(const float4*)(src + 4);
      }
    }
    const char* xb = (const char*)&xs[p & 1][0];
    #pragma unroll
    for (int k8 = 0; k8 < 4; ++k8){
      const int ks = p * 4 + k8;
      // prefetch B for ks+1 into the other slot
      if (ks < 15){
        #pragma unroll
        for (int et = 0; et < 4; ++et)
          bb[(ks + 1) & 1][et] = *(const short8*)(W1b + (size_t)(ebase + et * 16 + arow) * DD
                                                  + (ks + 1) * 32 + kgrp * 8);
      }
      short8 a[4];
      #pragma unroll
      for (int mt = 0; mt < 4; ++mt){
        int row = mt * 16 + arow;
        a[mt] = *(const short8*)(xb + row * 256 + ((k8 * 64 + kgrp * 16) ^ ((row & 7) << 4)));
      }
      __builtin_amdgcn_s_setprio(1);
      #pragma unroll
      for (int mt = 0; mt < 4; ++mt)
        #pragma unroll
        for (int et = 0; et < 4; ++et)
          acc[mt][et] = __builtin_amdgcn_mfma_f32_16x16x32_bf16(a[mt], bb[ks & 1][et], acc[mt][et], 0, 0, 0);
      __builtin_amdgcn_s_setprio(0);
    }
    // write staged regs -> other buffer (its readers finished at prior barrier)
    if (p < 3){
      #pragma unroll
      for (int i = 0; i < 4; ++i){
        int row = i * 16 + srow;
        *(ushort8*)((char*)&xs[(p + 1) & 1][0] + row * 256 + ((scc << 4) ^ swz)) = pack8(nf[2*i], nf[2*i+1]);
      }
    }
    __syncthreads();
  }

  // epilogue: tanh + dot(w2), reduce over e
  float ps[4][4];
  #pragma unroll
  for (int mt = 0; mt < 4; ++mt)
    #pragma unroll
    for (int i = 0; i < 4; ++i) ps[mt][i] = 0.f;

  #pragma unroll
  for (int et = 0; et < 4; ++et){
    int e = ebase + et * 16 + arow;          // C/D col = lane&15
    float b1v = b1[e];
    float w2v = w2[e];
    #pragma unroll
    for (int mt = 0; mt < 4; ++mt){
      #pragma unroll
      for (int i = 0; i < 4; ++i){
        float g = acc[mt][et][i] + b1v;
        g = fminf(15.f, fmaxf(-15.f, g));
        float ex = __expf(2.f * g);
        ps[mt][i] += (1.f - 2.f / (ex + 1.f)) * w2v;   // tanh(g)*w2
      }
    }
  }
  #pragma unroll
  for (int mt = 0; mt < 4; ++mt)
    #pragma unroll
    for (int i = 0; i < 4; ++i){
      float v = ps[mt][i];
      v += __shfl_xor(v, 1);
      v += __shfl_xor(v, 2);
      v += __shfl_xor(v, 4);
      v += __shfl_xor(v, 8);
      ps[mt][i] = v;
    }
  // combine 4 waves via LDS (alias xs; all LDS reads done at last barrier)
  float* psum = (float*)&xs[0][0];           // [4][64]
  if ((lane & 15) == 0){
    #pragma unroll
    for (int mt = 0; mt < 4; ++mt)
      #pragma unroll
      for (int i = 0; i < 4; ++i)
        psum[wv * 64 + mt * 16 + (lane >> 4) * 4 + i] = ps[mt][i];
  }
  __syncthreads();
  if (t < 64){
    float s = psum[t] + psum[64 + t] + psum[128 + t] + psum[192 + t];
    scorep[(size_t)ec * MTOT + m0 + t] = s;  // pre-softmax partial; b2 softmax-invariant
  }
}

// ---- kernel 3: sum e-chunk partials + row softmax -> w ----
__global__ void softmax_kernel(const float* __restrict__ scorep, float* __restrict__ wout){
  const int b = blockIdx.x;
  const int t = threadIdx.x;                 // 256
  float v[8];
  #pragma unroll
  for (int i = 0; i < 8; ++i){
    int m = b * SS + t + i * 256;
    v[i] = scorep[m] + scorep[MTOT + m];
  }
  float m = v[0];
  #pragma unroll
  for (int i = 1; i < 8; ++i) m = fmaxf(m, v[i]);
  #pragma unroll
  for (int msk = 32; msk >= 1; msk >>= 1) m = fmaxf(m, __shfl_xor(m, msk));
  __shared__ float redm[4], reds[4];
  if ((t & 63) == 0) redm[t >> 6] = m;
  __syncthreads();
  m = fmaxf(fmaxf(redm[0], redm[1]), fmaxf(redm[2], redm[3]));
  float s = 0.f;
  #pragma unroll
  for (int i = 0; i < 8; ++i){ v[i] = __expf(v[i] - m); s += v[i]; }
  #pragma unroll
  for (int msk = 32; msk >= 1; msk >>= 1) s += __shfl_xor(s, msk);
  if ((t & 63) == 0) reds[t >> 6] = s;
  __syncthreads();
  s = reds[0] + reds[1] + reds[2] + reds[3];
  float inv = 1.f / s;
  #pragma unroll
  for (int i = 0; i < 8; ++i) wout[(size_t)b * SS + t + i * 256] = v[i] * inv;
}

// ---- kernel 4: ctx partials (no atomics) ----
// grid 512 = 64 b x 8 s-chunks of 256; 512 thr = 4 s-substreams x 128 d-threads (float4)
__global__ void ctx_partial_kernel(const float* __restrict__ x, const float* __restrict__ wout,
                                   float* __restrict__ ctxp){
  __shared__ float red[4][512];
  const int t   = threadIdx.x;
  const int sub = t >> 7;                    // 0..3 (wave-uniform)
  const int dt  = t & 127;                   // d = dt*4
  const int b   = blockIdx.x >> 3;
  const int sc  = blockIdx.x & 7;
  const float* xb = x + (size_t)b * SS * DD;
  const int s0 = sc * 256 + sub * 64;
  float4 acc = {0.f, 0.f, 0.f, 0.f};
  for (int s = s0; s < s0 + 64; ++s){
    float wv = wout[(size_t)b * SS + s];     // wave-uniform -> scalar load
    float4 xv = *(const float4*)(xb + (size_t)s * DD + dt * 4);
    acc.x += wv * xv.x; acc.y += wv * xv.y; acc.z += wv * xv.z; acc.w += wv * xv.w;
  }
  *(float4*)&red[sub][dt * 4] = acc;
  __syncthreads();
  if (t < 128){
    float4 r0 = *(const float4*)&red[0][t * 4];
    float4 r1 = *(const float4*)&red[1][t * 4];
    float4 r2 = *(const float4*)&red[2][t * 4];
    float4 r3 = *(const float4*)&red[3][t * 4];
    float4 o = { r0.x+r1.x+r2.x+r3.x, r0.y+r1.y+r2.y+r3.y,
                 r0.z+r1.z+r2.z+r3.z, r0.w+r1.w+r2.w+r3.w };
    *(float4*)&ctxp[((size_t)(b * 8 + sc)) * DD + t * 4] = o;
  }
}

// ---- kernel 5: reduce ctx partials -> d_out ----
__global__ void ctx_reduce_kernel(const float* __restrict__ ctxp, float* __restrict__ ctx){
  int i = blockIdx.x * blockDim.x + threadIdx.x;   // 32768
  int b = i >> 9;
  int d = i & 511;
  float s = 0.f;
  #pragma unroll
  for (int sc = 0; sc < 8; ++sc) s += ctxp[((size_t)(b * 8 + sc)) * DD + d];
  ctx[(size_t)b * DD + d] = s;
}

extern "C" void kernel_launch(void* const* d_in, const int* in_sizes, int n_in,
                              void* d_out, int out_size, void* d_ws, size_t ws_size,
                              hipStream_t stream){
  const float* x  = (const float*)d_in[0];
  const float* W1 = (const float*)d_in[1];
  const float* b1 = (const float*)d_in[2];
  const float* w2 = (const float*)d_in[3];
  // d_in[4] = b2: softmax-invariant, unused.

  float* ctx  = (float*)d_out;                         // [64*512]
  float* wout = (float*)d_out + BB * DD;               // [64*2048]

  unsigned short* W1b = (unsigned short*)d_ws;                         // 512 KB
  float* scorep = (float*)((char*)d_ws + (512u << 10));                // 2 x 131072 f32 = 1 MB
  float* ctxp   = (float*)((char*)d_ws + (512u << 10) + (1024u << 10)); // 512 x 512 f32 = 1 MB

  hipLaunchKernelGGL(cvt_w1_kernel,     dim3(256),  dim3(256), 0, stream, W1, W1b);
  hipLaunchKernelGGL(scores_kernel,     dim3(4096), dim3(256), 0, stream, x, W1b, b1, w2, scorep);
  hipLaunchKernelGGL(softmax_kernel,    dim3(64),   dim3(256), 0, stream, scorep, wout);
  hipLaunchKernelGGL(ctx_partial_kernel,dim3(512),  dim3(512), 0, stream, x, wout, ctxp);
  hipLaunchKernelGGL(ctx_reduce_kernel, dim3(128),  dim3(256), 0, stream, ctxp, ctx);
}

// Round 3
// 162.963 us; speedup vs baseline: 1.3752x; 1.3752x over previous
//
#include <hip/hip_runtime.h>
#include <hip/hip_bf16.h>

#define BB 64
#define SS 2048
#define DD 512
#define MTOT (BB * SS)          // 131072 rows

typedef __attribute__((ext_vector_type(8))) short short8;            // 8 bf16
typedef __attribute__((ext_vector_type(8))) unsigned short ushort8;
typedef __attribute__((ext_vector_type(4))) float f32x4;

__device__ __forceinline__ unsigned short f2bf(float f){
  union { float f; unsigned int u; } a; a.f = f;
  unsigned int r = a.u + 0x7fffu + ((a.u >> 16) & 1u);  // RNE
  return (unsigned short)(r >> 16);
}

__device__ __forceinline__ ushort8 pack8(float4 a, float4 b){
  ushort8 u;
  u[0]=f2bf(a.x); u[1]=f2bf(a.y); u[2]=f2bf(a.z); u[3]=f2bf(a.w);
  u[4]=f2bf(b.x); u[5]=f2bf(b.y); u[6]=f2bf(b.z); u[7]=f2bf(b.w);
  return u;
}

__device__ __forceinline__ void gload_lds16(const unsigned short* g, unsigned short* l){
  __builtin_amdgcn_global_load_lds(
      (const __attribute__((address_space(1))) unsigned int*)g,
      (__attribute__((address_space(3))) unsigned int*)l, 16, 0, 0);
}

// ---- kernel 1: W1 fp32 -> bf16, PRE-SWIZZLED per-step tile layout ----
// Layout: [step s (16)][granule g (2048)] of 16B granules; granule (s,g) holds
// W1 row e=(g&511)^kc (kc=g>>9), k-elems [s*32+kc*8, +8). Then scores' B
// staging is a fully linear global_load_lds and ds_reads use g=kc*512+(e^kc).
__global__ void cvt_w1_kernel(const float* __restrict__ W1, unsigned short* __restrict__ W1s){
  int i = blockIdx.x * blockDim.x + threadIdx.x;   // 32768 = 16 steps * 2048 granules
  int s  = i >> 11;
  int g  = i & 2047;
  int kc = g >> 9;
  int e  = (g & 511) ^ kc;
  const float* src = W1 + (size_t)e * DD + s * 32 + kc * 8;
  float4 f0 = *(const float4*)src;
  float4 f1 = *(const float4*)(src + 4);
  *(ushort8*)(W1s + (size_t)i * 8) = pack8(f0, f1);
}

// ---- kernel 2: scores = sum_e tanh(x@W1^T + b1)[.,e] * w2[e] ----
// BM=64, BN=512 (full e), BK=32, 16 steps. 512 thr / 8 waves, wave wid owns
// e in [wid*64, +64): per-wave 64x64 tile = acc[4][4] f32x4 (64 regs).
// LDS per buffer: A granules [0,256) bytes [0,4096) swizzled kc*64+(row^kc);
//                 B granules bytes [4096,36864) swizzled kc*512+(e^kc).
// Double-buffered (72KB) -> 2 blocks/CU; launch_bounds forces VGPR<=128.
__launch_bounds__(512, 4)
__global__ void scores_kernel(const float* __restrict__ x,
                              const unsigned short* __restrict__ W1s,
                              const float* __restrict__ b1,
                              const float* __restrict__ w2,
                              float* __restrict__ scorep){
  __shared__ __align__(16) unsigned short lds[2][18432];   // 2 x 36 KB

  const int t    = threadIdx.x;
  const int lane = t & 63;
  const int wid  = t >> 6;
  const int m0   = blockIdx.x * 64;
  const int arow = lane & 15;
  const int kgrp = lane >> 4;

  f32x4 acc[4][4];
  #pragma unroll
  for (int mt = 0; mt < 4; ++mt)
    #pragma unroll
    for (int et = 0; et < 4; ++et)
      acc[mt][et] = (f32x4){0.f, 0.f, 0.f, 0.f};

  // A staging map (threads < 256): row = t>>2 (0..63), kc = t&3
  const int srow = t >> 2;
  const int skc  = t & 3;
  const float* asrc0 = x + (size_t)(m0 + srow) * DD + skc * 8;
  // A LDS write byte offset (swizzled granule)
  const int awoff = ((skc << 6) + (srow ^ skc)) << 4;

  // B staging: wave wid issues 4 gload_lds, j-th covers granules [(wid*4+j)*64, +64)
  // source is linear in the pre-swizzled W1s: step block = 32768 B
  const unsigned short* bsrc0 = W1s + ((size_t)((wid << 2) << 6) + lane) * 8;

  // ---- prologue: stage tile 0 ----
  #pragma unroll
  for (int j = 0; j < 4; ++j)
    gload_lds16(bsrc0 + j * 512, &lds[0][2048 + ((wid << 2) + j) * 512]);
  if (t < 256){
    float4 f0 = *(const float4*)asrc0;
    float4 f1 = *(const float4*)(asrc0 + 4);
    *(ushort8*)((char*)&lds[0][0] + awoff) = pack8(f0, f1);
  }
  __syncthreads();

  // ---- main loop: 16 k-steps of 32 ----
  for (int s = 0; s < 16; ++s){
    unsigned short* cur = &lds[s & 1][0];
    unsigned short* nxt = &lds[(s + 1) & 1][0];

    // issue staging for s+1 (globals first: longest latency)
    float4 f0, f1;
    if (s < 15){
      const unsigned short* bs = bsrc0 + (size_t)(s + 1) * 16384;  // 32768B = 16384 ushorts
      #pragma unroll
      for (int j = 0; j < 4; ++j)
        gload_lds16(bs + j * 512, nxt + 2048 + ((wid << 2) + j) * 512);
      if (t < 256){
        const float* as = asrc0 + (s + 1) * 32;
        f0 = *(const float4*)as;
        f1 = *(const float4*)(as + 4);
      }
    }

    // fragment reads (conflict-minimal swizzled)
    short8 af[4], bf[4];
    #pragma unroll
    for (int mt = 0; mt < 4; ++mt){
      int row = mt * 16 + arow;
      af[mt] = *(const short8*)((char*)cur + (((kgrp << 6) + (row ^ kgrp)) << 4));
    }
    #pragma unroll
    for (int et = 0; et < 4; ++et){
      int e = (wid << 6) + (et << 4) + arow;
      bf[et] = *(const short8*)((char*)cur + 4096 + (((kgrp << 9) + (e ^ kgrp)) << 4));
    }

    __builtin_amdgcn_s_setprio(1);
    #pragma unroll
    for (int mt = 0; mt < 4; ++mt)
      #pragma unroll
      for (int et = 0; et < 4; ++et)
        acc[mt][et] = __builtin_amdgcn_mfma_f32_16x16x32_bf16(af[mt], bf[et], acc[mt][et], 0, 0, 0);
    __builtin_amdgcn_s_setprio(0);

    // convert + write A for s+1 (vmcnt wait inserted here by compiler)
    if (s < 15 && t < 256)
      *(ushort8*)((char*)nxt + awoff) = pack8(f0, f1);

    __syncthreads();
  }

  // ---- epilogue: tanh + dot(w2), reduce over e ----
  float ps[4][4];
  #pragma unroll
  for (int mt = 0; mt < 4; ++mt)
    #pragma unroll
    for (int i = 0; i < 4; ++i) ps[mt][i] = 0.f;

  #pragma unroll
  for (int et = 0; et < 4; ++et){
    int e = (wid << 6) + (et << 4) + arow;     // C/D col = lane&15
    float b1v = b1[e];
    float w2v = w2[e];
    #pragma unroll
    for (int mt = 0; mt < 4; ++mt){
      #pragma unroll
      for (int i = 0; i < 4; ++i){
        float g = acc[mt][et][i] + b1v;
        g = fminf(15.f, fmaxf(-15.f, g));
        float ex = __expf(2.f * g);
        ps[mt][i] += (1.f - 2.f / (ex + 1.f)) * w2v;   // tanh(g)*w2
      }
    }
  }
  #pragma unroll
  for (int mt = 0; mt < 4; ++mt)
    #pragma unroll
    for (int i = 0; i < 4; ++i){
      float v = ps[mt][i];
      v += __shfl_xor(v, 1);
      v += __shfl_xor(v, 2);
      v += __shfl_xor(v, 4);
      v += __shfl_xor(v, 8);
      ps[mt][i] = v;
    }
  float* psum = (float*)&lds[0][0];            // [8][64]; safe after final barrier
  if ((lane & 15) == 0){
    #pragma unroll
    for (int mt = 0; mt < 4; ++mt)
      #pragma unroll
      for (int i = 0; i < 4; ++i)
        psum[wid * 64 + mt * 16 + (lane >> 4) * 4 + i] = ps[mt][i];
  }
  __syncthreads();
  if (t < 64){
    float ssum = 0.f;
    #pragma unroll
    for (int w = 0; w < 8; ++w) ssum += psum[w * 64 + t];
    scorep[m0 + t] = ssum;    // full pre-softmax score; b2 softmax-invariant
  }
}

// ---- kernel 3: row softmax -> w ----
__global__ void softmax_kernel(const float* __restrict__ scorep, float* __restrict__ wout){
  const int b = blockIdx.x;
  const int t = threadIdx.x;                 // 256
  float v[8];
  #pragma unroll
  for (int i = 0; i < 8; ++i) v[i] = scorep[(size_t)b * SS + t + i * 256];
  float m = v[0];
  #pragma unroll
  for (int i = 1; i < 8; ++i) m = fmaxf(m, v[i]);
  #pragma unroll
  for (int msk = 32; msk >= 1; msk >>= 1) m = fmaxf(m, __shfl_xor(m, msk));
  __shared__ float redm[4], reds[4];
  if ((t & 63) == 0) redm[t >> 6] = m;
  __syncthreads();
  m = fmaxf(fmaxf(redm[0], redm[1]), fmaxf(redm[2], redm[3]));
  float s = 0.f;
  #pragma unroll
  for (int i = 0; i < 8; ++i){ v[i] = __expf(v[i] - m); s += v[i]; }
  #pragma unroll
  for (int msk = 32; msk >= 1; msk >>= 1) s += __shfl_xor(s, msk);
  if ((t & 63) == 0) reds[t >> 6] = s;
  __syncthreads();
  s = reds[0] + reds[1] + reds[2] + reds[3];
  float inv = 1.f / s;
  #pragma unroll
  for (int i = 0; i < 8; ++i) wout[(size_t)b * SS + t + i * 256] = v[i] * inv;
}

// ---- kernel 4: ctx partials (no atomics) ----
__global__ void ctx_partial_kernel(const float* __restrict__ x, const float* __restrict__ wout,
                                   float* __restrict__ ctxp){
  __shared__ float red[4][512];
  const int t   = threadIdx.x;
  const int sub = t >> 7;                    // 0..3 (wave-uniform)
  const int dt  = t & 127;                   // d = dt*4
  const int b   = blockIdx.x >> 3;
  const int sc  = blockIdx.x & 7;
  const float* xb = x + (size_t)b * SS * DD;
  const int s0 = sc * 256 + sub * 64;
  float4 acc = {0.f, 0.f, 0.f, 0.f};
  for (int s = s0; s < s0 + 64; ++s){
    float wv = wout[(size_t)b * SS + s];     // wave-uniform -> scalar load
    float4 xv = *(const float4*)(xb + (size_t)s * DD + dt * 4);
    acc.x += wv * xv.x; acc.y += wv * xv.y; acc.z += wv * xv.z; acc.w += wv * xv.w;
  }
  *(float4*)&red[sub][dt * 4] = acc;
  __syncthreads();
  if (t < 128){
    float4 r0 = *(const float4*)&red[0][t * 4];
    float4 r1 = *(const float4*)&red[1][t * 4];
    float4 r2 = *(const float4*)&red[2][t * 4];
    float4 r3 = *(const float4*)&red[3][t * 4];
    float4 o = { r0.x+r1.x+r2.x+r3.x, r0.y+r1.y+r2.y+r3.y,
                 r0.z+r1.z+r2.z+r3.z, r0.w+r1.w+r2.w+r3.w };
    *(float4*)&ctxp[((size_t)(b * 8 + sc)) * DD + t * 4] = o;
  }
}

// ---- kernel 5: reduce ctx partials -> d_out ----
__global__ void ctx_reduce_kernel(const float* __restrict__ ctxp, float* __restrict__ ctx){
  int i = blockIdx.x * blockDim.x + threadIdx.x;   // 32768
  int b = i >> 9;
  int d = i & 511;
  float s = 0.f;
  #pragma unroll
  for (int sc = 0; sc < 8; ++sc) s += ctxp[((size_t)(b * 8 + sc)) * DD + d];
  ctx[(size_t)b * DD + d] = s;
}

extern "C" void kernel_launch(void* const* d_in, const int* in_sizes, int n_in,
                              void* d_out, int out_size, void* d_ws, size_t ws_size,
                              hipStream_t stream){
  const float* x  = (const float*)d_in[0];
  const float* W1 = (const float*)d_in[1];
  const float* b1 = (const float*)d_in[2];
  const float* w2 = (const float*)d_in[3];
  // d_in[4] = b2: softmax-invariant, unused.

  float* ctx  = (float*)d_out;                         // [64*512]
  float* wout = (float*)d_out + BB * DD;               // [64*2048]

  // ws layout (phase-disjoint reuse):
  //   scores phase: W1s [0, 512K), scorep [512K, 1M)
  //   ctx phase:    ctxp [0, 1M)  (W1s/scorep dead by then; same-stream ordering)
  unsigned short* W1s = (unsigned short*)d_ws;
  float* scorep = (float*)((char*)d_ws + (512u << 10));
  float* ctxp   = (float*)d_ws;

  hipLaunchKernelGGL(cvt_w1_kernel,      dim3(128),  dim3(256), 0, stream, W1, W1s);
  hipLaunchKernelGGL(scores_kernel,      dim3(2048), dim3(512), 0, stream, x, W1s, b1, w2, scorep);
  hipLaunchKernelGGL(softmax_kernel,     dim3(64),   dim3(256), 0, stream, scorep, wout);
  hipLaunchKernelGGL(ctx_partial_kernel, dim3(512),  dim3(512), 0, stream, x, wout, ctxp);
  hipLaunchKernelGGL(ctx_reduce_kernel,  dim3(128),  dim3(256), 0, stream, ctxp, ctx);
}